// Round 1
// baseline (2158.014 us; speedup 1.0000x reference)
//
#include <hip/hip_runtime.h>
#include <cstdint>
#include <cstddef>

typedef unsigned short u16;
typedef short v8s __attribute__((ext_vector_type(8)));
typedef float v4f __attribute__((ext_vector_type(4)));

__device__ __forceinline__ float b2f(u16 u) {
  return __uint_as_float(((uint32_t)u) << 16);
}
__device__ __forceinline__ u16 f2b(float f) {
  uint32_t x = __float_as_uint(f);
  uint32_t r = (x + 0x7fffu + ((x >> 16) & 1u)) >> 16;
  return (u16)r;
}

// ---------------- small prep kernels ----------------

__global__ void zero_i32(int* __restrict__ p, int n) {
  int i = blockIdx.x * blockDim.x + threadIdx.x;
  if (i < n) p[i] = 0;
}

__global__ void conv_nf_kernel(const float* __restrict__ nf, u16* __restrict__ A2, int n) {
  int i = blockIdx.x * blockDim.x + threadIdx.x;
  if (i >= n) return;
  int r = i >> 7, c = i & 127;
  A2[(size_t)r * 256 + c] = f2b(nf[i]);
}

__global__ void conv_rab_kernel(const float* __restrict__ er, const float* __restrict__ ea,
                                u16* __restrict__ rab, int n) {
  int i = blockIdx.x * blockDim.x + threadIdx.x;
  if (i >= n) return;
  int e = i >> 6, k = i & 63;
  float v = (k < 32) ? er[(size_t)e * 32 + k] : ea[(size_t)e * 32 + (k - 32)];
  rab[i] = f2b(v);
}

__global__ void src2_kernel(const int* __restrict__ src, int* __restrict__ src2, int n) {
  int i = blockIdx.x * blockDim.x + threadIdx.x;
  if (i < n) src2[i] = src[src[i]];
}

// W is [fin_total, fout] row-major fp32. dst is [n_rows, dst_ld] bf16, transposed (dst[n][k]).
__global__ void prep_weight(const float* __restrict__ W, int fout, int k_src_off, int k_valid,
                            u16* __restrict__ dst, int dst_ld, int dst_koff,
                            int n_rows, int k_cols) {
  int i = blockIdx.x * blockDim.x + threadIdx.x;
  if (i >= n_rows * k_cols) return;
  int n = i / k_cols, kk = i - n * k_cols;
  float v = 0.f;
  if (n < fout && kk < k_valid) v = W[(size_t)(k_src_off + kk) * fout + n];
  dst[(size_t)n * dst_ld + dst_koff + kk] = f2b(v);
}

__global__ void prep_bias(const float* __restrict__ a, const float* __restrict__ b,
                          float* __restrict__ dst, int fout, int npad) {
  int i = blockIdx.x * blockDim.x + threadIdx.x;
  if (i >= npad) return;
  float v = 0.f;
  if (i < fout) { v = a[i]; if (b) v += b[i]; }
  dst[i] = v;
}

// ---------------- CSR build ----------------

__global__ void hist_kernel(const int* __restrict__ dst, int* __restrict__ counts, int n) {
  int i = blockIdx.x * blockDim.x + threadIdx.x;
  if (i < n) atomicAdd(&counts[dst[i]], 1);
}

__global__ __launch_bounds__(1024) void scan_kernel(const int* __restrict__ counts,
                                                    int* __restrict__ offsets, int n) {
  __shared__ int sd[1024];
  __shared__ int srun;
  int t = threadIdx.x;
  if (t == 0) { srun = 0; offsets[0] = 0; }
  __syncthreads();
  for (int base = 0; base < n; base += 1024) {
    int x = (base + t < n) ? counts[base + t] : 0;
    sd[t] = x;
    __syncthreads();
    for (int o = 1; o < 1024; o <<= 1) {
      int y = (t >= o) ? sd[t - o] : 0;
      __syncthreads();
      sd[t] += y;
      __syncthreads();
    }
    int run = srun;
    if (base + t < n) offsets[base + t + 1] = run + sd[t];
    __syncthreads();
    if (t == 1023) srun = run + sd[1023];
    __syncthreads();
  }
}

__global__ void copy_i32(const int* __restrict__ a, int* __restrict__ b, int n) {
  int i = blockIdx.x * blockDim.x + threadIdx.x;
  if (i < n) b[i] = a[i];
}

__global__ void fill_kernel(const int* __restrict__ dst, int* __restrict__ cursor,
                            int* __restrict__ elist, int n) {
  int i = blockIdx.x * blockDim.x + threadIdx.x;
  if (i < n) {
    int d = dst[i];
    int pos = atomicAdd(&cursor[d], 1);
    elist[pos] = i;
  }
}

// ---------------- segment sum over CSR (one wave per node) ----------------

__global__ __launch_bounds__(256) void msgsum_kernel(const u16* __restrict__ sub,
    const int* __restrict__ elist, const int* __restrict__ offsets,
    u16* __restrict__ msgs, int nn) {
  int w = threadIdx.x >> 6, lane = threadIdx.x & 63;
  int n = blockIdx.x * 4 + w;
  if (n >= nn) return;
  int beg = offsets[n], end = offsets[n + 1];
  float a0 = 0.f, a1 = 0.f, a2 = 0.f;
  for (int j = beg; j < end; ++j) {
    int e = elist[j];
    const u16* s = sub + (size_t)e * 192;
    a0 += b2f(s[lane]);
    a1 += b2f(s[lane + 64]);
    a2 += b2f(s[lane + 128]);
  }
  size_t o = (size_t)n * 192 + lane;
  msgs[o] = f2b(a0);
  msgs[o + 64] = f2b(a1);
  msgs[o + 128] = f2b(a2);
}

// ---------------- generic MFMA GEMM ----------------
// C[m,n] = act( A[m,:K]@Wt[n,:K]^T + bias[n] + G1[idx1[m],n] + G2[idx2[m],n] ) + Res[m,n]
// A: bf16 [M, lda] (uses cols 0..Kp-1), Wt: bf16 [Np, Kp] (pre-transposed, zero-padded),
// block tile 128x64, BK=64, 4 waves, 16x16x32 bf16 MFMA.
// ACT: 0=none 1=relu 2=sigmoid
template<int ACT, bool BIAS, bool G1E, bool G2E, bool RESE, bool OBF>
__global__ __launch_bounds__(256) void gemm_kernel(
    const u16* __restrict__ A, int lda, int M,
    const u16* __restrict__ Wt, int Kp,
    const float* __restrict__ bias,
    const u16* __restrict__ G1, const int* __restrict__ idx1, int ldg1,
    const u16* __restrict__ G2, const int* __restrict__ idx2, int ldg2,
    const float* __restrict__ Res, int ldr,
    void* __restrict__ Out, int ldc)
{
  __shared__ u16 Asl[128 * 72];   // +8 pad -> 2-way-max bank aliasing on reads
  __shared__ u16 Bsl[64 * 72];
  const int m0 = blockIdx.x * 128;
  const int n0 = blockIdx.y * 64;
  const int tid = threadIdx.x;
  const int w = tid >> 6, lane = tid & 63;
  const int quad = lane >> 4, lr = lane & 15;
  const int rs = w * 32;

  v4f acc[2][4] = {};

  const int cw = tid & 7;        // 16B chunk in row
  const int r0 = tid >> 3;       // 0..31

  for (int k0 = 0; k0 < Kp; k0 += 64) {
#pragma unroll
    for (int i = 0; i < 4; ++i) {
      int row = r0 + 32 * i;
      int mrow = m0 + row; if (mrow >= M) mrow = M - 1;   // clamp: safe, unused rows
      *(v8s*)&Asl[row * 72 + cw * 8] =
          *(const v8s*)(A + (size_t)mrow * lda + k0 + cw * 8);
    }
#pragma unroll
    for (int i = 0; i < 2; ++i) {
      int row = r0 + 32 * i;
      *(v8s*)&Bsl[row * 72 + cw * 8] =
          *(const v8s*)(Wt + (size_t)(n0 + row) * Kp + k0 + cw * 8);
    }
    __syncthreads();
#pragma unroll
    for (int kk = 0; kk < 64; kk += 32) {
      v8s a0 = *(const v8s*)&Asl[(rs + lr) * 72 + kk + quad * 8];
      v8s a1 = *(const v8s*)&Asl[(rs + 16 + lr) * 72 + kk + quad * 8];
#pragma unroll
      for (int t = 0; t < 4; ++t) {
        v8s b = *(const v8s*)&Bsl[(t * 16 + lr) * 72 + kk + quad * 8];
        acc[0][t] = __builtin_amdgcn_mfma_f32_16x16x32_bf16(a0, b, acc[0][t], 0, 0, 0);
        acc[1][t] = __builtin_amdgcn_mfma_f32_16x16x32_bf16(a1, b, acc[1][t], 0, 0, 0);
      }
    }
    __syncthreads();
  }

  // epilogue: D[row=quad*4+r][col=lr] per 16x16 tile
#pragma unroll
  for (int s = 0; s < 2; ++s) {
#pragma unroll
    for (int r = 0; r < 4; ++r) {
      int m = m0 + rs + s * 16 + quad * 4 + r;
      bool valid = m < M;
      int mc = valid ? m : M - 1;
      int i1 = 0, i2 = 0;
      if (G1E) i1 = idx1[mc];
      if (G2E) i2 = idx2[mc];
#pragma unroll
      for (int t = 0; t < 4; ++t) {
        int n = n0 + t * 16 + lr;
        float v = acc[s][t][r];
        if (BIAS) v += bias[n];
        if (G1E) v += b2f(G1[(size_t)i1 * ldg1 + n]);
        if (G2E) v += b2f(G2[(size_t)i2 * ldg2 + n]);
        if (ACT == 1) v = v > 0.f ? v : 0.f;
        if (ACT == 2) v = 1.f / (1.f + __expf(-v));
        if (RESE) v += Res[(size_t)mc * ldr + n];
        if (valid) {
          if (OBF) ((u16*)Out)[(size_t)m * ldc + n] = f2b(v);
          else     ((float*)Out)[(size_t)m * ldc + n] = v;
        }
      }
    }
  }
}

// ---------------- launch ----------------

extern "C" void kernel_launch(void* const* d_in, const int* in_sizes, int n_in,
                              void* d_out, int out_size, void* d_ws, size_t ws_size,
                              hipStream_t stream) {
  const int N = in_sizes[0] / 128;   // 50000
  const int E = in_sizes[3] / 2;     // 800000

  const float* nf     = (const float*)d_in[0];
  const float* er     = (const float*)d_in[1];
  const float* ea     = (const float*)d_in[2];
  const int*   ei     = (const int*)d_in[3];
  const float* w1     = (const float*)d_in[4];
  const float* b1     = (const float*)d_in[5];
  const float* w2a    = (const float*)d_in[6];
  const float* b2a    = (const float*)d_in[7];
  const float* w2b    = (const float*)d_in[8];
  const float* b2b    = (const float*)d_in[9];
  const float* w2c    = (const float*)d_in[10];
  const float* b2c    = (const float*)d_in[11];
  const float* w2d    = (const float*)d_in[12];
  const float* b2d    = (const float*)d_in[13];
  const float* wself  = (const float*)d_in[14];
  const float* bself  = (const float*)d_in[15];
  const float* wneigh = (const float*)d_in[16];
  const float* bneigh = (const float*)d_in[17];
  const float* wedge  = (const float*)d_in[18];
  const float* bedge  = (const float*)d_in[19];
  const int* srcI = ei;
  const int* dstI = ei + E;

  char* ws = (char*)d_ws;
  size_t off = 0;
  auto carve = [&](size_t bytes) -> char* {
    char* p = ws + off;
    off = (off + bytes + 255) & ~((size_t)255);
    return p;
  };
  u16* A2   = (u16*)carve((size_t)N * 256 * 2);   // [nf_bf16 | m_bf16]
  u16* S    = (u16*)carve((size_t)N * 192 * 2);
  u16* msgs = (u16*)carve((size_t)N * 192 * 2);
  u16* rab  = (u16*)carve((size_t)E * 64 * 2);
  int* src2    = (int*)carve((size_t)E * 4);
  int* counts  = (int*)carve((size_t)(N + 1) * 4);
  int* offsets = (int*)carve((size_t)(N + 1) * 4);
  int* cursor  = (int*)carve((size_t)(N + 1) * 4);
  int* elist   = (int*)carve((size_t)E * 4);
  u16* WtS   = (u16*)carve(192 * 128 * 2);
  u16* Wtsub = (u16*)carve(192 * 64 * 2);
  u16* Wt2a  = (u16*)carve(128 * 192 * 2);
  u16* Wt2b  = (u16*)carve(64 * 128 * 2);
  u16* Wt2c  = (u16*)carve(64 * 64 * 2);
  u16* Wt2d  = (u16*)carve(128 * 64 * 2);
  u16* Wtcb  = (u16*)carve(128 * 256 * 2);
  u16* WteA  = (u16*)carve(320 * 128 * 2);
  u16* WteB  = (u16*)carve(320 * 128 * 2);
  u16* WteC  = (u16*)carve(320 * 64 * 2);
  float* b1p  = (float*)carve(192 * 4);
  float* b2ap = (float*)carve(128 * 4);
  float* b2bp = (float*)carve(64 * 4);
  float* b2cp = (float*)carve(64 * 4);
  float* b2dp = (float*)carve(128 * 4);
  float* bcb  = (float*)carve(128 * 4);
  float* bep  = (float*)carve(320 * 4);
  char* big = carve((size_t)E * 192 * 2 + 65536);  // sub; reused for P/Q/h* after msgsum
  u16* sub = (u16*)big;
  u16* P   = (u16*)big;
  u16* Q   = (u16*)(big + (size_t)N * 320 * 2);
  u16* h1  = (u16*)(big + (size_t)2 * N * 320 * 2);
  u16* h2  = (u16*)(big + (size_t)2 * N * 320 * 2 + (size_t)N * 128 * 2);
  u16* h3  = (u16*)(big + (size_t)2 * N * 320 * 2 + (size_t)N * 128 * 2 + (size_t)N * 64 * 2);
  float* outN = (float*)d_out;
  float* outE = (float*)d_out + (size_t)N * 128;
  (void)ws_size; (void)n_in; (void)out_size;

  const int T = 256;
  // ---- weight/bias prep (bf16, transposed, zero-padded to x64) ----
  prep_weight<<<(192*128 + T-1)/T, T, 0, stream>>>(w1,   192,   0, 128, WtS,  128,   0, 192, 128);
  prep_weight<<<(192*64  + T-1)/T, T, 0, stream>>>(w1,   192, 128,  64, Wtsub, 64,   0, 192,  64);
  prep_weight<<<(128*192 + T-1)/T, T, 0, stream>>>(w2a,  112,   0, 192, Wt2a, 192,   0, 128, 192);
  prep_weight<<<(64*128  + T-1)/T, T, 0, stream>>>(w2b,   32,   0, 112, Wt2b, 128,   0,  64, 128);
  prep_weight<<<(64*64   + T-1)/T, T, 0, stream>>>(w2c,   64,   0,  32, Wt2c,  64,   0,  64,  64);
  prep_weight<<<(128*64  + T-1)/T, T, 0, stream>>>(w2d,  128,   0,  64, Wt2d,  64,   0, 128,  64);
  prep_weight<<<(128*128 + T-1)/T, T, 0, stream>>>(wself, 128,  0, 128, Wtcb, 256,   0, 128, 128);
  prep_weight<<<(128*128 + T-1)/T, T, 0, stream>>>(wneigh,128,  0, 128, Wtcb, 256, 128, 128, 128);
  prep_weight<<<(320*128 + T-1)/T, T, 0, stream>>>(wedge, 320,  0, 128, WteA, 128,   0, 320, 128);
  prep_weight<<<(320*128 + T-1)/T, T, 0, stream>>>(wedge, 320,128, 128, WteB, 128,   0, 320, 128);
  prep_weight<<<(320*64  + T-1)/T, T, 0, stream>>>(wedge, 320,256,  64, WteC,  64,   0, 320,  64);
  prep_bias<<<1, 192, 0, stream>>>(b1,   nullptr, b1p,  192, 192);
  prep_bias<<<1, 128, 0, stream>>>(b2a,  nullptr, b2ap, 112, 128);
  prep_bias<<<1,  64, 0, stream>>>(b2b,  nullptr, b2bp,  32,  64);
  prep_bias<<<1,  64, 0, stream>>>(b2c,  nullptr, b2cp,  64,  64);
  prep_bias<<<1, 128, 0, stream>>>(b2d,  nullptr, b2dp, 128, 128);
  prep_bias<<<1, 128, 0, stream>>>(bself, bneigh, bcb,  128, 128);
  prep_bias<<<1, 320, 0, stream>>>(bedge, nullptr, bep,  320, 320);

  // ---- conversions / index prep ----
  conv_nf_kernel <<<(N*128 + T-1)/T, T, 0, stream>>>(nf, A2, N * 128);
  conv_rab_kernel<<<(E*64  + T-1)/T, T, 0, stream>>>(er, ea, rab, E * 64);
  src2_kernel    <<<(E + T-1)/T, T, 0, stream>>>(srcI, src2, E);

  // ---- CSR over dst ----
  zero_i32   <<<(N + T-1)/T, T, 0, stream>>>(counts, N);
  hist_kernel<<<(E + T-1)/T, T, 0, stream>>>(dstI, counts, E);
  scan_kernel<<<1, 1024, 0, stream>>>(counts, offsets, N);
  copy_i32   <<<(N + T-1)/T, T, 0, stream>>>(offsets, cursor, N);
  fill_kernel<<<(E + T-1)/T, T, 0, stream>>>(dstI, cursor, elist, E);

  const int gN = (N + 127) / 128;   // 391
  const int gE = E / 128;           // 6250

  // 1: S = nf@w1[:128] + b1          [N,192] bf16
  gemm_kernel<0, true, false, false, false, true><<<dim3(gN, 3), T, 0, stream>>>(
      A2, 256, N, WtS, 128, b1p,
      nullptr, nullptr, 0, nullptr, nullptr, 0, nullptr, 0, S, 192);
  // 2: sub = sigmoid(rab@w1[128:] + S[src2])   [E,192] bf16
  gemm_kernel<2, false, true, false, false, true><<<dim3(gE, 3), T, 0, stream>>>(
      rab, 64, E, Wtsub, 64, nullptr,
      S, src2, 192, nullptr, nullptr, 0, nullptr, 0, sub, 192);
  // messages = segment_sum(sub, dst)
  msgsum_kernel<<<(N + 3) / 4, T, 0, stream>>>(sub, elist, offsets, msgs, N);
  // 3..6: mlp2
  gemm_kernel<1, true, false, false, false, true><<<dim3(gN, 2), T, 0, stream>>>(
      msgs, 192, N, Wt2a, 192, b2ap,
      nullptr, nullptr, 0, nullptr, nullptr, 0, nullptr, 0, h1, 128);
  gemm_kernel<1, true, false, false, false, true><<<dim3(gN, 1), T, 0, stream>>>(
      h1, 128, N, Wt2b, 128, b2bp,
      nullptr, nullptr, 0, nullptr, nullptr, 0, nullptr, 0, h2, 64);
  gemm_kernel<1, true, false, false, false, true><<<dim3(gN, 1), T, 0, stream>>>(
      h2, 64, N, Wt2c, 64, b2cp,
      nullptr, nullptr, 0, nullptr, nullptr, 0, nullptr, 0, h3, 64);
  gemm_kernel<0, true, false, false, false, true><<<dim3(gN, 2), T, 0, stream>>>(
      h3, 64, N, Wt2d, 64, b2dp,
      nullptr, nullptr, 0, nullptr, nullptr, 0, nullptr, 0, A2 + 128, 256);  // m -> A2[:,128:]
  // 7: P = nf@wedge[:128] + bedge    [N,320] bf16
  gemm_kernel<0, true, false, false, false, true><<<dim3(gN, 5), T, 0, stream>>>(
      A2, 256, N, WteA, 128, bep,
      nullptr, nullptr, 0, nullptr, nullptr, 0, nullptr, 0, P, 320);
  // 8: Q = nf@wedge[128:256]         [N,320] bf16
  gemm_kernel<0, false, false, false, false, true><<<dim3(gN, 5), T, 0, stream>>>(
      A2, 256, N, WteB, 128, nullptr,
      nullptr, nullptr, 0, nullptr, nullptr, 0, nullptr, 0, Q, 320);
  // 9: node_upd = sigmoid([nf|m]@[wself;wneigh] + bself+bneigh) + nf   fp32 -> d_out
  gemm_kernel<2, true, false, false, true, false><<<dim3(gN, 2), T, 0, stream>>>(
      A2, 256, N, Wtcb, 256, bcb,
      nullptr, nullptr, 0, nullptr, nullptr, 0, nf, 128, outN, 128);
  // 10: edge_upd = sigmoid(rab@wedge[256:] + P[src] + Q[dst])   fp32 -> d_out+N*128
  gemm_kernel<2, false, true, true, false, false><<<dim3(gE, 5), T, 0, stream>>>(
      rab, 64, E, WteC, 64, nullptr,
      P, srcI, 320, Q, dstI, 320, nullptr, 0, outE, 320);
}